// Round 11
// baseline (847.397 us; speedup 1.0000x reference)
//
#include <hip/hip_runtime.h>
#include <math.h>

#define BB 1024
#define NN 1024
#define DD 64
#define MARGIN_V 0.5f
#define EPS_V 1e-6f
#define QSPLIT 4               // blocks per batch row
#define QCOLS (NN / QSPLIT)    // 256 columns per block
#define ROWFLOATS (NN * DD)    // 65536 floats per output row

typedef float f32x4 __attribute__((ext_vector_type(4)));

// ---------------------------------------------------------------------------
// k_init: zero the cross-block counters (ws is poisoned once by the harness
// and never re-poisoned between replays, so we must reset every call).
// ---------------------------------------------------------------------------
__global__ __launch_bounds__(1024) void k_init(int* __restrict__ row_cnt,
                                               int* __restrict__ done_cnt)
{
    row_cnt[threadIdx.x] = 0;
    if (threadIdx.x == 0) done_cnt[0] = 0;
}

// ---------------------------------------------------------------------------
// k_fused: 4096 blocks = 4 per batch row.
//  Phase 1 (R6-verified dist core): coalesced group-of-16 layout, batched
//   shfl reduces, per-block partials {loss, best(score,idx), valid}.
//  Phase 2 (fused tail, G16 release/acquire via __threadfence + device-scope
//   atomics): last-of-row block merges the 4 quarter partials (first-index
//   tie-break), writes has_valid, and gathers negative[sel] -> out row,
//   OVERLAPPED with other rows' dist work (k_dist only used ~65% of the
//   achievable read BW, so the gather traffic rides along ~free).
//   Globally-last block does a deterministic fixed-partition loss reduce.
// ---------------------------------------------------------------------------
__global__ __launch_bounds__(256) void k_fused(const float* __restrict__ a,
                                               const float* __restrict__ p,
                                               const float* __restrict__ g,
                                               float* __restrict__ ws_loss,
                                               float* __restrict__ ws_score,
                                               int* __restrict__ ws_idx,
                                               int* __restrict__ ws_valid,
                                               int* __restrict__ row_cnt,
                                               int* __restrict__ done_cnt,
                                               float* __restrict__ out_loss,
                                               float* __restrict__ out_hn,
                                               float* __restrict__ out_hasvalid)
{
    const int blk  = blockIdx.x;       // 0..4095
    const int b    = blk >> 2;
    const int q    = blk & 3;
    const int tid  = threadIdx.x;
    const int lane = tid & 63;
    const int wave = tid >> 6;         // 0..3
    const int grp  = lane >> 4;        // 0..3
    const int gl   = lane & 15;        // lane within 16-lane group
    const int group = wave * 4 + grp;  // 0..15

    const size_t base  = (size_t)b * (NN * DD);
    const int    ncol0 = q * QCOLS + group;   // group's cols: ncol0 + i*16, i=0..15

    float loss_acc   = 0.f;
    float best_score = -INFINITY;
    int   best_idx   = 0x7fffffff;

    #pragma unroll 1
    for (int h = 0; h < 2; ++h) {
        // ---- load burst: 24 coalesced loads, zero cross-lane ops ----
        f32x4 va[8], vp[8], vg[8];
        #pragma unroll
        for (int i = 0; i < 8; ++i) {
            const int n = ncol0 + (h * 8 + i) * 16;
            const size_t off = base + (size_t)n * DD + (size_t)gl * 4;
            va[i] = __builtin_nontemporal_load((const f32x4*)(a + off));
            vp[i] = __builtin_nontemporal_load((const f32x4*)(p + off));
            vg[i] = *(const f32x4*)(g + off);
        }

        // ---- pure-VALU accumulate ----
        float accp[8], accn[8];
        #pragma unroll
        for (int i = 0; i < 8; ++i) {
            float sp = 0.f, sn = 0.f, t;
            #pragma unroll
            for (int e = 0; e < 4; ++e) {
                t = va[i][e] - vp[i][e] + EPS_V; sp += t * t;
                t = va[i][e] - vg[i][e] + EPS_V; sn += t * t;
            }
            accp[i] = sp; accn[i] = sn;
        }

        // ---- batched 16-lane-group reduces ----
        #pragma unroll
        for (int i = 0; i < 8; ++i) {
            #pragma unroll
            for (int m = 1; m < 16; m <<= 1) {
                accp[i] += __shfl_xor(accp[i], m, 64);
                accn[i] += __shfl_xor(accn[i], m, 64);
            }
        }

        // ---- tail: lane gl==i owns column (h*8+i) ----
        #pragma unroll
        for (int i = 0; i < 8; ++i) {
            if (gl == i) {
                const int n = ncol0 + (h * 8 + i) * 16;
                const float diff = MARGIN_V + sqrtf(accp[i]) - sqrtf(accn[i]);
                loss_acc += fmaxf(diff, 0.f);
                const float sc = (diff > 0.f) ? sqrtf(accn[i]) : -INFINITY;
                if (sc > best_score || (sc == best_score && n < best_idx)) {
                    best_score = sc; best_idx = n;
                }
            }
        }
    }

    // ---- wave reduce: sum(loss), argmax(score), first-index tie-break ----
    for (int m = 1; m < 64; m <<= 1) {
        loss_acc += __shfl_xor(loss_acc, m, 64);
        const float so = __shfl_xor(best_score, m, 64);
        const int   io = __shfl_xor(best_idx, m, 64);
        if (so > best_score || (so == best_score && io < best_idx)) {
            best_score = so; best_idx = io;
        }
    }

    __shared__ float s_loss[4];
    __shared__ float s_score[4];
    __shared__ int   s_idx[4];
    __shared__ int   s_flags[2];   // [0]=last-of-row, [1]=last-overall
    __shared__ int   s_sel;
    if ((tid & 63) == 0) {
        s_loss[wave]  = loss_acc;
        s_score[wave] = best_score;
        s_idx[wave]   = best_idx;
    }
    __syncthreads();
    if (tid == 0) {
        float ls = 0.f, bs = -INFINITY;
        int   bi = 0x7fffffff;
        for (int k = 0; k < 4; ++k) {
            ls += s_loss[k];
            const float sc = s_score[k]; const int ix = s_idx[k];
            if (sc > bs || (sc == bs && ix < bi)) { bs = sc; bi = ix; }
        }
        ws_loss[blk]  = ls;
        ws_score[blk] = bs;
        ws_idx[blk]   = bi;
        ws_valid[blk] = (bs > -INFINITY) ? 1 : 0;

        // release partials, then count this block done for its row
        __threadfence();
        const int o = atomicAdd(&row_cnt[b], 1);
        int lastrow = (o == 3);
        int sel = 0;
        if (lastrow) {
            __threadfence();   // acquire: the other 3 blocks' partials
            float mbs = -INFINITY; int mbi = 0x7fffffff; int av = 0;
            for (int qq = 0; qq < QSPLIT; ++qq) {
                const int idx = b * QSPLIT + qq;
                const float sc = ws_score[idx];
                const int   ix = ws_idx[idx];
                if (sc > mbs || (sc == mbs && ix < mbi)) { mbs = sc; mbi = ix; }
                av |= ws_valid[idx];
            }
            sel = mbi;
            out_hasvalid[b] = av ? 1.0f : 0.0f;
        }
        const int d = atomicAdd(done_cnt, 1);
        s_flags[0] = lastrow;
        s_flags[1] = (d == QSPLIT * BB - 1);
        s_sel = sel;
    }
    __syncthreads();

    // ---- fused gather: last-of-row block copies negative[sel] -> out row ----
    if (s_flags[0]) {
        const float* __restrict__ src = g      + (size_t)s_sel * ROWFLOATS;
        float* __restrict__       dst = out_hn + (size_t)b    * ROWFLOATS;
        #pragma unroll 8
        for (int k2 = 0; k2 < ROWFLOATS / 256; ++k2) {
            const int i2 = k2 * 256 + tid;      // coalesced; dst 4B-misaligned -> scalar NT
            __builtin_nontemporal_store(src[i2], dst + i2);
        }
    }

    // ---- fused loss mean: globally-last block, deterministic reduction ----
    if (s_flags[1]) {
        __threadfence();   // acquire all 4096 ws_loss
        __shared__ float s_red[256];
        float v = 0.f;
        #pragma unroll
        for (int j = 0; j < (QSPLIT * BB) / 256; ++j)
            v += ws_loss[tid * ((QSPLIT * BB) / 256) + j];   // fixed partition, fixed order
        s_red[tid] = v;
        __syncthreads();
        for (int st = 128; st > 0; st >>= 1) {
            if (tid < st) s_red[tid] += s_red[tid + st];
            __syncthreads();
        }
        if (tid == 0) out_loss[0] = s_red[0] / (float)((size_t)BB * NN);
    }
}

extern "C" void kernel_launch(void* const* d_in, const int* in_sizes, int n_in,
                              void* d_out, int out_size, void* d_ws, size_t ws_size,
                              hipStream_t stream) {
    const float* anchor   = (const float*)d_in[0];
    const float* positive = (const float*)d_in[1];
    const float* negative = (const float*)d_in[2];
    float* out = (float*)d_out;

    // out layout: [0] loss | [1 .. 1+B*N*D) hard_neg | [1+B*N*D .. +B) has_valid
    float* out_loss     = out;
    float* out_hard_neg = out + 1;
    float* out_hasvalid = out + 1 + (size_t)BB * NN * DD;

    // ws layout: 4096 loss | 4096 score | 4096 idx | 4096 valid | 1024 row_cnt | 1 done_cnt
    float* ws_loss  = (float*)d_ws;
    float* ws_score = ws_loss + BB * QSPLIT;
    int*   ws_idx   = (int*)(ws_score + BB * QSPLIT);
    int*   ws_valid = ws_idx + BB * QSPLIT;
    int*   row_cnt  = ws_valid + BB * QSPLIT;
    int*   done_cnt = row_cnt + BB;

    k_init<<<dim3(1), dim3(1024), 0, stream>>>(row_cnt, done_cnt);
    k_fused<<<dim3(BB * QSPLIT), dim3(256), 0, stream>>>(anchor, positive, negative,
                                                         ws_loss, ws_score, ws_idx, ws_valid,
                                                         row_cnt, done_cnt,
                                                         out_loss, out_hard_neg, out_hasvalid);
}

// Round 12
// 233.112 us; speedup vs baseline: 3.6351x; 3.6351x over previous
//
#include <hip/hip_runtime.h>
#include <math.h>

#define BB 1024
#define NN 1024
#define DD 64
#define MARGIN_V 0.5f
#define EPS_V 1e-6f
#define QSPLIT 4               // blocks per batch row in k_dist
#define QCOLS (NN / QSPLIT)    // 256 columns per block (64 per wave)
#define NCHUNK 16              // chunks per wave; 4 columns (1KB/array) each
#define ROWFLOATS (NN * DD)    // 65536 floats per output row

typedef float f32x4 __attribute__((ext_vector_type(4)));
typedef __attribute__((address_space(1))) const unsigned char glb_u8;
typedef __attribute__((address_space(3))) unsigned char lds_u8;

// ---------------------------------------------------------------------------
// Kernel 1 (R10-verified, fastest measured k_dist: 187.9-191.0 us):
// 4096 blocks = 4 per batch row; 4 waves/block, each wave owns 64 columns and
// runs an INDEPENDENT global_load_lds DMA pipeline (no barriers in the loop).
// Per chunk (4 cols): 3 DMA calls (a/p/g, 1KB contiguous each). T3/T4
// schedule: issue chunk k+2, then s_waitcnt vmcnt(6) -- counted, never 0
// mid-loop -- so ~6KB/wave stays in flight across every consume.
// Consume: group grp reads col (ch*4+grp) via ds_read_b128, 4-step shfl
// reduce, owner lane gl==ch updates loss/argmax; final 64-lane wave reduce +
// 4-wave LDS merge writes per-block partials.
// ---------------------------------------------------------------------------
__global__ __launch_bounds__(256) void k_dist(const float* __restrict__ a,
                                              const float* __restrict__ p,
                                              const float* __restrict__ g,
                                              float* __restrict__ ws_loss,
                                              float* __restrict__ ws_score,
                                              int* __restrict__ ws_idx,
                                              int* __restrict__ ws_valid)
{
    __shared__ __align__(16) unsigned char smem[4][4][3][1024]; // [wave][buf][arr][1KB] = 48KB

    const int blk  = blockIdx.x;       // 0..4095
    const int b    = blk >> 2;
    const int q    = blk & 3;
    const int tid  = threadIdx.x;
    const int lane = tid & 63;
    const int wave = tid >> 6;         // 0..3
    const int grp  = lane >> 4;        // 0..3
    const int gl   = lane & 15;        // lane within 16-lane group

    const int wcol0 = q * QCOLS + wave * 64;   // wave's columns [wcol0, wcol0+64)
    const size_t baseByte = ((size_t)b * NN * DD + (size_t)wcol0 * DD) * 4u + (size_t)lane * 16u;
    const unsigned char* aB = (const unsigned char*)a + baseByte;
    const unsigned char* pB = (const unsigned char*)p + baseByte;
    const unsigned char* gB = (const unsigned char*)g + baseByte;

    float loss_acc   = 0.f;
    float best_score = -INFINITY;
    int   best_idx   = 0x7fffffff;

    auto STAGE = [&](int ch, int buf) {
        const size_t o = (size_t)ch * 1024u;
        __builtin_amdgcn_global_load_lds((glb_u8*)(aB + o), (lds_u8*)&smem[wave][buf][0][0], 16, 0, 0);
        __builtin_amdgcn_global_load_lds((glb_u8*)(pB + o), (lds_u8*)&smem[wave][buf][1][0], 16, 0, 0);
        __builtin_amdgcn_global_load_lds((glb_u8*)(gB + o), (lds_u8*)&smem[wave][buf][2][0], 16, 0, 0);
    };

    auto CONSUME = [&](int ch, int buf) {
        const int off = grp * 256 + gl * 16;
        const f32x4 va = *(const f32x4*)&smem[wave][buf][0][off];
        const f32x4 vp = *(const f32x4*)&smem[wave][buf][1][off];
        const f32x4 vg = *(const f32x4*)&smem[wave][buf][2][off];
        float sp = 0.f, sn = 0.f, t;
        #pragma unroll
        for (int e = 0; e < 4; ++e) {
            t = va[e] - vp[e] + EPS_V; sp += t * t;
            t = va[e] - vg[e] + EPS_V; sn += t * t;
        }
        #pragma unroll
        for (int m = 1; m < 16; m <<= 1) {
            sp += __shfl_xor(sp, m, 64);
            sn += __shfl_xor(sn, m, 64);
        }
        if (gl == ch) {                       // unique owner lane per (chunk, group)
            const int n = wcol0 + ch * 4 + grp;
            const float diff = MARGIN_V + sqrtf(sp) - sqrtf(sn);
            loss_acc += fmaxf(diff, 0.f);
            const float sc = (diff > 0.f) ? sqrtf(sn) : -INFINITY;
            if (sc > best_score || (sc == best_score && n < best_idx)) {
                best_score = sc; best_idx = n;
            }
        }
    };

    STAGE(0, 0);
    STAGE(1, 1);

    #pragma unroll 1
    for (int k = 0; k < NCHUNK - 2; ++k) {
        STAGE(k + 2, (k + 2) & 3);                      // outstanding: k, k+1, k+2 (9 loads)
        asm volatile("s_waitcnt vmcnt(6)" ::: "memory");// oldest 3 (chunk k) landed
        __builtin_amdgcn_sched_barrier(0);
        CONSUME(k, k & 3);
    }
    asm volatile("s_waitcnt vmcnt(3)" ::: "memory");
    __builtin_amdgcn_sched_barrier(0);
    CONSUME(NCHUNK - 2, (NCHUNK - 2) & 3);
    asm volatile("s_waitcnt vmcnt(0)" ::: "memory");
    __builtin_amdgcn_sched_barrier(0);
    CONSUME(NCHUNK - 1, (NCHUNK - 1) & 3);

    for (int m = 1; m < 64; m <<= 1) {
        loss_acc += __shfl_xor(loss_acc, m, 64);
        const float so = __shfl_xor(best_score, m, 64);
        const int   io = __shfl_xor(best_idx, m, 64);
        if (so > best_score || (so == best_score && io < best_idx)) {
            best_score = so; best_idx = io;
        }
    }

    __shared__ float s_loss[4];
    __shared__ float s_score[4];
    __shared__ int   s_idx[4];
    if ((tid & 63) == 0) {
        s_loss[wave]  = loss_acc;
        s_score[wave] = best_score;
        s_idx[wave]   = best_idx;
    }
    __syncthreads();
    if (tid == 0) {
        float ls = 0.f, bs = -INFINITY;
        int   bi = 0x7fffffff;
        for (int k = 0; k < 4; ++k) {
            ls += s_loss[k];
            const float sc = s_score[k]; const int ix = s_idx[k];
            if (sc > bs || (sc == bs && ix < bi)) { bs = sc; bi = ix; }
        }
        ws_loss[blk]  = ls;
        ws_score[blk] = bs;
        ws_idx[blk]   = bi;
        ws_valid[blk] = (bs > -INFINITY) ? 1 : 0;
    }
}

// ---------------------------------------------------------------------------
// Kernel 2: gather + merged tail in ONE dispatch, grid (33, BB).
//  Blocks x<32: merge row b's 4 partials inline (8 broadcast scalar loads,
//   deterministic, redundant across the 32 blocks -> no extra dispatch),
//   then copy the 1/32 slice of negative[sel] -> out row b. Coalesced scalar
//   NT stores (dst is 4B-misaligned vs 16B; output never re-read).
//  Blocks x==32: block (32,b) writes has_valid[b]; block (32,0) additionally
//   does the deterministic fixed-partition loss mean.
// ---------------------------------------------------------------------------
__global__ __launch_bounds__(256) void k_gm(const float* __restrict__ g,
                                            const float* __restrict__ ws_loss,
                                            const float* __restrict__ ws_score,
                                            const int* __restrict__ ws_idx,
                                            const int* __restrict__ ws_valid,
                                            float* __restrict__ out_loss,
                                            float* __restrict__ out_hn,
                                            float* __restrict__ out_hasvalid)
{
    const int x   = blockIdx.x;    // 0..32
    const int b   = blockIdx.y;    // 0..1023
    const int tid = threadIdx.x;

    if (x < 32) {
        // inline merge (first-index tie-break) -- same values in all lanes
        float bs = -INFINITY; int bi = 0x7fffffff;
        #pragma unroll
        for (int qq = 0; qq < QSPLIT; ++qq) {
            const float sc = ws_score[b * QSPLIT + qq];
            const int   ix = ws_idx[b * QSPLIT + qq];
            if (sc > bs || (sc == bs && ix < bi)) { bs = sc; bi = ix; }
        }
        const float* __restrict__ src = g      + (size_t)bi * ROWFLOATS;
        float* __restrict__       dst = out_hn + (size_t)b  * ROWFLOATS;
        const int t = x * 256 + tid;   // 0..8191
        #pragma unroll
        for (int k = 0; k < ROWFLOATS / 8192; ++k) {
            const int idx = t + k * 8192;
            __builtin_nontemporal_store(src[idx], dst + idx);
        }
    } else {
        if (tid == 0) {
            int av = 0;
            #pragma unroll
            for (int qq = 0; qq < QSPLIT; ++qq) av |= ws_valid[b * QSPLIT + qq];
            out_hasvalid[b] = av ? 1.0f : 0.0f;
        }
        if (b == 0) {
            __shared__ float s_red[256];
            float v = 0.f;
            #pragma unroll
            for (int j = 0; j < (QSPLIT * BB) / 256; ++j)
                v += ws_loss[tid * ((QSPLIT * BB) / 256) + j];   // fixed partition/order
            s_red[tid] = v;
            __syncthreads();
            for (int st = 128; st > 0; st >>= 1) {
                if (tid < st) s_red[tid] += s_red[tid + st];
                __syncthreads();
            }
            if (tid == 0) out_loss[0] = s_red[0] / (float)((size_t)BB * NN);
        }
    }
}

extern "C" void kernel_launch(void* const* d_in, const int* in_sizes, int n_in,
                              void* d_out, int out_size, void* d_ws, size_t ws_size,
                              hipStream_t stream) {
    const float* anchor   = (const float*)d_in[0];
    const float* positive = (const float*)d_in[1];
    const float* negative = (const float*)d_in[2];
    float* out = (float*)d_out;

    // out layout: [0] loss | [1 .. 1+B*N*D) hard_neg | [1+B*N*D .. +B) has_valid
    float* out_loss     = out;
    float* out_hard_neg = out + 1;
    float* out_hasvalid = out + 1 + (size_t)BB * NN * DD;

    // ws layout: 4096 loss | 4096 score | 4096 idx | 4096 valid
    float* ws_loss  = (float*)d_ws;
    float* ws_score = ws_loss + BB * QSPLIT;
    int*   ws_idx   = (int*)(ws_score + BB * QSPLIT);
    int*   ws_valid = ws_idx + BB * QSPLIT;

    k_dist<<<dim3(BB * QSPLIT), dim3(256), 0, stream>>>(anchor, positive, negative,
                                                        ws_loss, ws_score, ws_idx, ws_valid);
    k_gm<<<dim3(33, BB), dim3(256), 0, stream>>>(negative, ws_loss, ws_score, ws_idx, ws_valid,
                                                 out_loss, out_hard_neg, out_hasvalid);
}

// Round 13
// 222.559 us; speedup vs baseline: 3.8075x; 1.0474x over previous
//
#include <hip/hip_runtime.h>
#include <math.h>

#define BB 1024
#define NN 1024
#define DD 64
#define MARGIN_V 0.5f
#define EPS_V 1e-6f
#define QSPLIT 4               // blocks per batch row in k_dist
#define QCOLS (NN / QSPLIT)    // 256 columns per block (64 per wave)
#define NCHUNK 16              // chunks per wave; 4 columns (1KB/array) each
#define ROWFLOATS (NN * DD)    // 65536 floats per output row

typedef float f32x4 __attribute__((ext_vector_type(4)));
typedef __attribute__((address_space(1))) const unsigned char glb_u8;
typedef __attribute__((address_space(3))) unsigned char lds_u8;

// ---------------------------------------------------------------------------
// Kernel 1 (fastest measured k_dist: 187.9-191.0 us, R10/R12):
// 4096 blocks = 4 per batch row; 4 waves/block, each wave owns 64 columns and
// runs an INDEPENDENT global_load_lds DMA pipeline (no barriers in the loop).
// Per chunk (4 cols): 3 DMA calls (a/p/g, 1KB contiguous each). T3/T4
// schedule: issue chunk k+2, then s_waitcnt vmcnt(6) -- counted, never 0
// mid-loop -- so ~6KB/wave stays in flight across every consume.
// NEW vs R12: a/p DMAs use aux=2 (gfx950 CPol NT) so the two single-use
// streams don't evict `negative` (256MB == L3 size) -- keeps the gather's
// source L3-resident (R6 showed this halves the tail cost).
// ---------------------------------------------------------------------------
__global__ __launch_bounds__(256) void k_dist(const float* __restrict__ a,
                                              const float* __restrict__ p,
                                              const float* __restrict__ g,
                                              float* __restrict__ ws_loss,
                                              float* __restrict__ ws_score,
                                              int* __restrict__ ws_idx,
                                              int* __restrict__ ws_valid)
{
    __shared__ __align__(16) unsigned char smem[4][4][3][1024]; // [wave][buf][arr][1KB] = 48KB

    const int blk  = blockIdx.x;       // 0..4095
    const int b    = blk >> 2;
    const int q    = blk & 3;
    const int tid  = threadIdx.x;
    const int lane = tid & 63;
    const int wave = tid >> 6;         // 0..3
    const int grp  = lane >> 4;        // 0..3
    const int gl   = lane & 15;        // lane within 16-lane group

    const int wcol0 = q * QCOLS + wave * 64;   // wave's columns [wcol0, wcol0+64)
    const size_t baseByte = ((size_t)b * NN * DD + (size_t)wcol0 * DD) * 4u + (size_t)lane * 16u;
    const unsigned char* aB = (const unsigned char*)a + baseByte;
    const unsigned char* pB = (const unsigned char*)p + baseByte;
    const unsigned char* gB = (const unsigned char*)g + baseByte;

    float loss_acc   = 0.f;
    float best_score = -INFINITY;
    int   best_idx   = 0x7fffffff;

    auto STAGE = [&](int ch, int buf) {
        const size_t o = (size_t)ch * 1024u;
        // aux=2 -> NT (gfx94x/gfx950 CPol: SC0=1, NT=2, SC1=16): stream a/p
        __builtin_amdgcn_global_load_lds((glb_u8*)(aB + o), (lds_u8*)&smem[wave][buf][0][0], 16, 0, 2);
        __builtin_amdgcn_global_load_lds((glb_u8*)(pB + o), (lds_u8*)&smem[wave][buf][1][0], 16, 0, 2);
        __builtin_amdgcn_global_load_lds((glb_u8*)(gB + o), (lds_u8*)&smem[wave][buf][2][0], 16, 0, 0);
    };

    auto CONSUME = [&](int ch, int buf) {
        const int off = grp * 256 + gl * 16;
        const f32x4 va = *(const f32x4*)&smem[wave][buf][0][off];
        const f32x4 vp = *(const f32x4*)&smem[wave][buf][1][off];
        const f32x4 vg = *(const f32x4*)&smem[wave][buf][2][off];
        float sp = 0.f, sn = 0.f, t;
        #pragma unroll
        for (int e = 0; e < 4; ++e) {
            t = va[e] - vp[e] + EPS_V; sp += t * t;
            t = va[e] - vg[e] + EPS_V; sn += t * t;
        }
        #pragma unroll
        for (int m = 1; m < 16; m <<= 1) {
            sp += __shfl_xor(sp, m, 64);
            sn += __shfl_xor(sn, m, 64);
        }
        if (gl == ch) {                       // unique owner lane per (chunk, group)
            const int n = wcol0 + ch * 4 + grp;
            const float diff = MARGIN_V + sqrtf(sp) - sqrtf(sn);
            loss_acc += fmaxf(diff, 0.f);
            const float sc = (diff > 0.f) ? sqrtf(sn) : -INFINITY;
            if (sc > best_score || (sc == best_score && n < best_idx)) {
                best_score = sc; best_idx = n;
            }
        }
    };

    STAGE(0, 0);
    STAGE(1, 1);

    #pragma unroll 1
    for (int k = 0; k < NCHUNK - 2; ++k) {
        STAGE(k + 2, (k + 2) & 3);                      // outstanding: k, k+1, k+2 (9 loads)
        asm volatile("s_waitcnt vmcnt(6)" ::: "memory");// oldest 3 (chunk k) landed
        __builtin_amdgcn_sched_barrier(0);
        CONSUME(k, k & 3);
    }
    asm volatile("s_waitcnt vmcnt(3)" ::: "memory");
    __builtin_amdgcn_sched_barrier(0);
    CONSUME(NCHUNK - 2, (NCHUNK - 2) & 3);
    asm volatile("s_waitcnt vmcnt(0)" ::: "memory");
    __builtin_amdgcn_sched_barrier(0);
    CONSUME(NCHUNK - 1, (NCHUNK - 1) & 3);

    for (int m = 1; m < 64; m <<= 1) {
        loss_acc += __shfl_xor(loss_acc, m, 64);
        const float so = __shfl_xor(best_score, m, 64);
        const int   io = __shfl_xor(best_idx, m, 64);
        if (so > best_score || (so == best_score && io < best_idx)) {
            best_score = so; best_idx = io;
        }
    }

    __shared__ float s_loss[4];
    __shared__ float s_score[4];
    __shared__ int   s_idx[4];
    if ((tid & 63) == 0) {
        s_loss[wave]  = loss_acc;
        s_score[wave] = best_score;
        s_idx[wave]   = best_idx;
    }
    __syncthreads();
    if (tid == 0) {
        float ls = 0.f, bs = -INFINITY;
        int   bi = 0x7fffffff;
        for (int k = 0; k < 4; ++k) {
            ls += s_loss[k];
            const float sc = s_score[k]; const int ix = s_idx[k];
            if (sc > bs || (sc == bs && ix < bi)) { bs = sc; bi = ix; }
        }
        ws_loss[blk]  = ls;
        ws_score[blk] = bs;
        ws_idx[blk]   = bi;
        ws_valid[blk] = (bs > -INFINITY) ? 1 : 0;
    }
}

// ---------------------------------------------------------------------------
// Kernel 2 (single block, 1024 threads): thread b merges its QSPLIT partials
// (first-index tie-break), writes sel/has_valid, block-reduces loss -> mean.
// ---------------------------------------------------------------------------
__global__ __launch_bounds__(1024) void k_merge(const float* __restrict__ ws_loss,
                                                const float* __restrict__ ws_score,
                                                const int* __restrict__ ws_idx,
                                                const int* __restrict__ ws_valid,
                                                float* __restrict__ out_loss,
                                                int* __restrict__ ws_sel,
                                                float* __restrict__ out_hasvalid)
{
    const int b = threadIdx.x;
    float ls = 0.f;
    float bs = -INFINITY;
    int   bi = 0x7fffffff;
    int   av = 0;
    for (int qq = 0; qq < QSPLIT; ++qq) {
        const int idx = b * QSPLIT + qq;
        const float sc = ws_score[idx];
        const int   ix = ws_idx[idx];
        if (sc > bs || (sc == bs && ix < bi)) { bs = sc; bi = ix; }
        ls += ws_loss[idx];
        av |= ws_valid[idx];
    }
    ws_sel[b] = bi;
    out_hasvalid[b] = av ? 1.0f : 0.0f;

    __shared__ float s[16];
    float v = ls;
    for (int m = 1; m < 64; m <<= 1) v += __shfl_xor(v, m, 64);
    if ((b & 63) == 0) s[b >> 6] = v;
    __syncthreads();
    if (b == 0) {
        float tot = 0.f;
        for (int k = 0; k < 16; ++k) tot += s[k];
        out_loss[0] = tot / (float)((size_t)BB * NN);
    }
}

// ---------------------------------------------------------------------------
// Kernel 3: hard_neg[b] = negative[sel_col[b]].  Scalar coalesced copies
// (dst is 4B-misaligned vs 16B). Non-temporal stores: output never re-read.
// Source should be largely L3-resident thanks to k_dist's NT a/p policy.
// ---------------------------------------------------------------------------
__global__ __launch_bounds__(256) void k_gather(const float* __restrict__ g,
                                                const int* __restrict__ ws_sel,
                                                float* __restrict__ out_hn)
{
    const int b   = blockIdx.y;
    const int sel = ws_sel[b];
    const float* __restrict__ src = g      + (size_t)sel * ROWFLOATS;
    float* __restrict__       dst = out_hn + (size_t)b   * ROWFLOATS;
    const int t = blockIdx.x * blockDim.x + threadIdx.x;   // 0..8191
    #pragma unroll
    for (int k = 0; k < ROWFLOATS / 8192; ++k) {
        const int idx = t + k * 8192;
        __builtin_nontemporal_store(src[idx], dst + idx);
    }
}

extern "C" void kernel_launch(void* const* d_in, const int* in_sizes, int n_in,
                              void* d_out, int out_size, void* d_ws, size_t ws_size,
                              hipStream_t stream) {
    const float* anchor   = (const float*)d_in[0];
    const float* positive = (const float*)d_in[1];
    const float* negative = (const float*)d_in[2];
    float* out = (float*)d_out;

    // out layout: [0] loss | [1 .. 1+B*N*D) hard_neg | [1+B*N*D .. +B) has_valid
    float* out_loss     = out;
    float* out_hard_neg = out + 1;
    float* out_hasvalid = out + 1 + (size_t)BB * NN * DD;

    // ws layout: 4096 loss | 4096 score | 4096 idx | 4096 valid | 1024 sel
    float* ws_loss  = (float*)d_ws;
    float* ws_score = ws_loss + BB * QSPLIT;
    int*   ws_idx   = (int*)(ws_score + BB * QSPLIT);
    int*   ws_valid = ws_idx + BB * QSPLIT;
    int*   ws_sel   = ws_valid + BB * QSPLIT;

    k_dist<<<dim3(BB * QSPLIT), dim3(256), 0, stream>>>(anchor, positive, negative,
                                                        ws_loss, ws_score, ws_idx, ws_valid);
    k_merge<<<dim3(1), dim3(1024), 0, stream>>>(ws_loss, ws_score, ws_idx, ws_valid,
                                                out_loss, ws_sel, out_hasvalid);
    k_gather<<<dim3(32, BB), dim3(256), 0, stream>>>(negative, ws_sel, out_hard_neg);
}

// Round 14
// 211.378 us; speedup vs baseline: 4.0089x; 1.0529x over previous
//
#include <hip/hip_runtime.h>
#include <math.h>

#define BB 1024
#define NN 1024
#define DD 64
#define MARGIN_V 0.5f
#define EPS_V 1e-6f
#define QSPLIT 4               // blocks per batch row in k_dist
#define QCOLS (NN / QSPLIT)    // 256 columns per block
#define ROWFLOATS (NN * DD)    // 65536 floats per output row

typedef float f32x4 __attribute__((ext_vector_type(4)));

// ---------------------------------------------------------------------------
// Kernel 1 (R6-verified, best composite: 213.3 us total): 4096 blocks = 4 per
// batch row. Coalesced group-of-16 layout (lane gl reads f32x4 of column n at
// elem gl*4 -> 1KB/wave-instr). Two halves; per half a 24-load burst with NO
// cross-lane ops inside (loads stay schedulable), then batched 16-lane-group
// shfl reduces. NT hints on a/p (single-use) keep `negative` (256MB == L3)
// resident for the gather -- measured tail 17us vs 27-42us for DMA variants.
// ---------------------------------------------------------------------------
__global__ __launch_bounds__(256) void k_dist(const float* __restrict__ a,
                                              const float* __restrict__ p,
                                              const float* __restrict__ g,
                                              float* __restrict__ ws_loss,
                                              float* __restrict__ ws_score,
                                              int* __restrict__ ws_idx,
                                              int* __restrict__ ws_valid)
{
    const int blk  = blockIdx.x;       // 0..4095
    const int b    = blk >> 2;
    const int q    = blk & 3;
    const int tid  = threadIdx.x;
    const int lane = tid & 63;
    const int wave = tid >> 6;         // 0..3
    const int grp  = lane >> 4;        // 0..3
    const int gl   = lane & 15;        // lane within 16-lane group
    const int group = wave * 4 + grp;  // 0..15

    const size_t base  = (size_t)b * (NN * DD);
    const int    ncol0 = q * QCOLS + group;   // group's cols: ncol0 + i*16, i=0..15

    float loss_acc   = 0.f;
    float best_score = -INFINITY;
    int   best_idx   = 0x7fffffff;

    #pragma unroll 1
    for (int h = 0; h < 2; ++h) {
        // ---- load burst: 24 independent coalesced loads, zero cross-lane ----
        f32x4 va[8], vp[8], vg[8];
        #pragma unroll
        for (int i = 0; i < 8; ++i) {
            const int n = ncol0 + (h * 8 + i) * 16;
            const size_t off = base + (size_t)n * DD + (size_t)gl * 4;
            va[i] = __builtin_nontemporal_load((const f32x4*)(a + off));
            vp[i] = __builtin_nontemporal_load((const f32x4*)(p + off));
            vg[i] = *(const f32x4*)(g + off);
        }

        // ---- pure-VALU accumulate (per-lane partials, static indices) ----
        float accp[8], accn[8];
        #pragma unroll
        for (int i = 0; i < 8; ++i) {
            float sp = 0.f, sn = 0.f, t;
            #pragma unroll
            for (int e = 0; e < 4; ++e) {
                t = va[i][e] - vp[i][e] + EPS_V; sp += t * t;
                t = va[i][e] - vg[i][e] + EPS_V; sn += t * t;
            }
            accp[i] = sp; accn[i] = sn;
        }

        // ---- batched 16-lane-group reduces (independent 4-deep chains) ----
        #pragma unroll
        for (int i = 0; i < 8; ++i) {
            #pragma unroll
            for (int m = 1; m < 16; m <<= 1) {
                accp[i] += __shfl_xor(accp[i], m, 64);
                accn[i] += __shfl_xor(accn[i], m, 64);
            }
        }

        // ---- tail: lane gl==i owns column (h*8+i) ----
        #pragma unroll
        for (int i = 0; i < 8; ++i) {
            if (gl == i) {
                const int n = ncol0 + (h * 8 + i) * 16;
                const float diff = MARGIN_V + sqrtf(accp[i]) - sqrtf(accn[i]);
                loss_acc += fmaxf(diff, 0.f);
                const float sc = (diff > 0.f) ? sqrtf(accn[i]) : -INFINITY;
                if (sc > best_score || (sc == best_score && n < best_idx)) {
                    best_score = sc; best_idx = n;
                }
            }
        }
    }

    // ---- wave reduce: sum(loss), argmax(score) with first-index tie-break ----
    for (int m = 1; m < 64; m <<= 1) {
        loss_acc += __shfl_xor(loss_acc, m, 64);
        const float so = __shfl_xor(best_score, m, 64);
        const int   io = __shfl_xor(best_idx, m, 64);
        if (so > best_score || (so == best_score && io < best_idx)) {
            best_score = so; best_idx = io;
        }
    }

    __shared__ float s_loss[4];
    __shared__ float s_score[4];
    __shared__ int   s_idx[4];
    if ((tid & 63) == 0) {
        s_loss[wave]  = loss_acc;
        s_score[wave] = best_score;
        s_idx[wave]   = best_idx;
    }
    __syncthreads();
    if (tid == 0) {
        float ls = 0.f, bs = -INFINITY;
        int   bi = 0x7fffffff;
        for (int k = 0; k < 4; ++k) {
            ls += s_loss[k];
            const float sc = s_score[k]; const int ix = s_idx[k];
            if (sc > bs || (sc == bs && ix < bi)) { bs = sc; bi = ix; }
        }
        ws_loss[blk]  = ls;
        ws_score[blk] = bs;
        ws_idx[blk]   = bi;
        ws_valid[blk] = (bs > -INFINITY) ? 1 : 0;
    }
}

// ---------------------------------------------------------------------------
// Kernel 2 (R12-verified): gather + merged tail in ONE dispatch, grid (33,BB).
//  Blocks x<32: merge row b's 4 partials inline (8 broadcast scalar loads,
//   deterministic, redundant across the 32 blocks -> kills the k_merge
//   dispatch), then copy the 1/32 slice of negative[sel] -> out row b.
//   Coalesced scalar NT stores (dst 4B-misaligned vs 16B; never re-read).
//  Blocks x==32: block (32,b) writes has_valid[b]; block (32,0) additionally
//   does the deterministic fixed-partition loss mean.
// ---------------------------------------------------------------------------
__global__ __launch_bounds__(256) void k_gm(const float* __restrict__ g,
                                            const float* __restrict__ ws_loss,
                                            const float* __restrict__ ws_score,
                                            const int* __restrict__ ws_idx,
                                            const int* __restrict__ ws_valid,
                                            float* __restrict__ out_loss,
                                            float* __restrict__ out_hn,
                                            float* __restrict__ out_hasvalid)
{
    const int x   = blockIdx.x;    // 0..32
    const int b   = blockIdx.y;    // 0..1023
    const int tid = threadIdx.x;

    if (x < 32) {
        // inline merge (first-index tie-break) -- same values in all lanes
        float bs = -INFINITY; int bi = 0x7fffffff;
        #pragma unroll
        for (int qq = 0; qq < QSPLIT; ++qq) {
            const float sc = ws_score[b * QSPLIT + qq];
            const int   ix = ws_idx[b * QSPLIT + qq];
            if (sc > bs || (sc == bs && ix < bi)) { bs = sc; bi = ix; }
        }
        const float* __restrict__ src = g      + (size_t)bi * ROWFLOATS;
        float* __restrict__       dst = out_hn + (size_t)b  * ROWFLOATS;
        const int t = x * 256 + tid;   // 0..8191
        #pragma unroll
        for (int k = 0; k < ROWFLOATS / 8192; ++k) {
            const int idx = t + k * 8192;
            __builtin_nontemporal_store(src[idx], dst + idx);
        }
    } else {
        if (tid == 0) {
            int av = 0;
            #pragma unroll
            for (int qq = 0; qq < QSPLIT; ++qq) av |= ws_valid[b * QSPLIT + qq];
            out_hasvalid[b] = av ? 1.0f : 0.0f;
        }
        if (b == 0) {
            __shared__ float s_red[256];
            float v = 0.f;
            #pragma unroll
            for (int j = 0; j < (QSPLIT * BB) / 256; ++j)
                v += ws_loss[tid * ((QSPLIT * BB) / 256) + j];   // fixed partition/order
            s_red[tid] = v;
            __syncthreads();
            for (int st = 128; st > 0; st >>= 1) {
                if (tid < st) s_red[tid] += s_red[tid + st];
                __syncthreads();
            }
            if (tid == 0) out_loss[0] = s_red[0] / (float)((size_t)BB * NN);
        }
    }
}

extern "C" void kernel_launch(void* const* d_in, const int* in_sizes, int n_in,
                              void* d_out, int out_size, void* d_ws, size_t ws_size,
                              hipStream_t stream) {
    const float* anchor   = (const float*)d_in[0];
    const float* positive = (const float*)d_in[1];
    const float* negative = (const float*)d_in[2];
    float* out = (float*)d_out;

    // out layout: [0] loss | [1 .. 1+B*N*D) hard_neg | [1+B*N*D .. +B) has_valid
    float* out_loss     = out;
    float* out_hard_neg = out + 1;
    float* out_hasvalid = out + 1 + (size_t)BB * NN * DD;

    // ws layout: 4096 loss | 4096 score | 4096 idx | 4096 valid
    float* ws_loss  = (float*)d_ws;
    float* ws_score = ws_loss + BB * QSPLIT;
    int*   ws_idx   = (int*)(ws_score + BB * QSPLIT);
    int*   ws_valid = ws_idx + BB * QSPLIT;

    k_dist<<<dim3(BB * QSPLIT), dim3(256), 0, stream>>>(anchor, positive, negative,
                                                        ws_loss, ws_score, ws_idx, ws_valid);
    k_gm<<<dim3(33, BB), dim3(256), 0, stream>>>(negative, ws_loss, ws_score, ws_idx, ws_valid,
                                                 out_loss, out_hard_neg, out_hasvalid);
}